// Round 1
// baseline (2002.519 us; speedup 1.0000x reference)
//
#include <hip/hip_runtime.h>
#include <math.h>

#define BDIM  4
#define NFEAT 2048
#define DDIM  256
#define KCENT 16384
#define TK    5
#define KB    64     // centroids per LDS tile
#define MBF   32     // features per block
#define FMAXV 3.402823466e+38f

// sum over 16-lane rows via DPP row_ror (VALU pipe only, no LDS)
__device__ __forceinline__ float red16(float v) {
  int t;
  t = __builtin_amdgcn_update_dpp(0, __float_as_int(v), 0x128, 0xF, 0xF, false); v += __int_as_float(t);
  t = __builtin_amdgcn_update_dpp(0, __float_as_int(v), 0x124, 0xF, 0xF, false); v += __int_as_float(t);
  t = __builtin_amdgcn_update_dpp(0, __float_as_int(v), 0x122, 0xF, 0xF, false); v += __int_as_float(t);
  t = __builtin_amdgcn_update_dpp(0, __float_as_int(v), 0x121, 0xF, 0xF, false); v += __int_as_float(t);
  return v;
}

// ---- c2[k] = sum(C[k,:]^2) -------------------------------------------------
__global__ __launch_bounds__(256) void k_c2(const float* __restrict__ C, float* __restrict__ c2) {
  const int w = threadIdx.x >> 6, l = threadIdx.x & 63;
  const int row = blockIdx.x * 4 + w;
  const float4 v = *(const float4*)(C + (size_t)row * DDIM + l * 4);
  float ss = v.x*v.x + v.y*v.y + v.z*v.z + v.w*v.w;
  ss = red16(ss);
  ss += __shfl_xor(ss, 16);
  ss += __shfl_xor(ss, 32);
  if (l == 0) c2[row] = ss;
}

// ---- fused distance + top5 + softmax + scatter -----------------------------
__global__ __launch_bounds__(256, 1) void k_main(
    const float* __restrict__ F, const float* __restrict__ A, const float* __restrict__ C,
    const float* __restrict__ c2ws, float* __restrict__ outG, float* __restrict__ outW)
{
  __shared__ float sC[2][KB][DDIM];     // 128 KB, double-buffered centroid tiles
  __shared__ float sC2[2][KB];
  __shared__ float sX2[MBF];
  __shared__ float candSq[MBF][4][TK];
  __shared__ int   candIx[MBF][4][TK];
  __shared__ float topP[MBF][TK];
  __shared__ int   topI[MBF][TK];
  __shared__ float sAtt[MBF];

  const int tid = threadIdx.x;
  const int w = tid >> 6, l = tid & 63;
  const int g = l >> 4, s = l & 15;        // 4 k-groups x 16 d-lanes
  const int b = blockIdx.x >> 6;
  const int fbase = (blockIdx.x & 63) * MBF;

  // features: 8 rows per wave, d-chunks spread over 16 lanes -> registers
  float4 xv[8][4];
#pragma unroll
  for (int j = 0; j < 8; ++j) {
    const float* fr = F + ((size_t)(b * NFEAT + fbase + w * 8 + j)) * DDIM;
#pragma unroll
    for (int r = 0; r < 4; ++r) xv[j][r] = *(const float4*)(fr + (s + 16 * r) * 4);
  }
  // x2 per feature
  {
    float ps[8];
#pragma unroll
    for (int j = 0; j < 8; ++j) {
      float p = 0.f;
#pragma unroll
      for (int r = 0; r < 4; ++r) {
        const float4 a = xv[j][r];
        p = fmaf(a.x, a.x, p); p = fmaf(a.y, a.y, p); p = fmaf(a.z, a.z, p); p = fmaf(a.w, a.w, p);
      }
      ps[j] = red16(p);
    }
    if (l == 0) {
#pragma unroll
      for (int j = 0; j < 8; ++j) sX2[w * 8 + j] = ps[j];
    }
  }

  auto stage = [&](int t, int bufi) {
    const float* gbase = C + (size_t)t * KB * DDIM;
#pragma unroll
    for (int i = 0; i < 16; ++i) {
      const int row = w * 16 + i;
      __builtin_amdgcn_global_load_lds(
          (const __attribute__((address_space(1))) void*)(gbase + row * DDIM + l * 4),
          (__attribute__((address_space(3))) void*)(&sC[bufi][row][0]), 16, 0, 0);
    }
    if (w == 0)
      __builtin_amdgcn_global_load_lds(
          (const __attribute__((address_space(1))) void*)(c2ws + t * KB + l),
          (__attribute__((address_space(3))) void*)(&sC2[bufi][0]), 4, 0, 0);
  };

  // per-lane top-5 (feature jj = s&7; lanes s>=8 are redundant duplicates)
  float t0v = FMAXV, t1v = FMAXV, t2v = FMAXV, t3v = FMAXV, t4v = FMAXV;
  int   i0 = -1, i1 = -1, i2 = -1, i3 = -1, i4 = -1;
  const int jj = s & 7;

  stage(0, 0);
  for (int t = 0; t < KCENT / KB; ++t) {
    __syncthreads();                       // tile t staged, prev compute done
    if (t + 1 < KCENT / KB) stage(t + 1, (t + 1) & 1);  // async, overlaps compute
    const int bi_ = t & 1;
    for (int li = 0; li < 16; ++li) {
      const int krow = li * 4 + g;
      const float* crow = &sC[bi_][krow][0];
      float acc[8] = {0, 0, 0, 0, 0, 0, 0, 0};
#pragma unroll
      for (int r = 0; r < 4; ++r) {
        const float4 cv = *(const float4*)(crow + (s + 16 * r) * 4);
#pragma unroll
        for (int j = 0; j < 8; ++j) {
          acc[j] = fmaf(xv[j][r].x, cv.x, acc[j]);
          acc[j] = fmaf(xv[j][r].y, cv.y, acc[j]);
          acc[j] = fmaf(xv[j][r].z, cv.z, acc[j]);
          acc[j] = fmaf(xv[j][r].w, cv.w, acc[j]);
        }
      }
#pragma unroll
      for (int j = 0; j < 8; ++j) acc[j] = red16(acc[j]);
      float dv = acc[0];
      dv = (jj == 1) ? acc[1] : dv; dv = (jj == 2) ? acc[2] : dv;
      dv = (jj == 3) ? acc[3] : dv; dv = (jj == 4) ? acc[4] : dv;
      dv = (jj == 5) ? acc[5] : dv; dv = (jj == 6) ? acc[6] : dv;
      dv = (jj == 7) ? acc[7] : dv;
      const float sq = sC2[bi_][krow] - 2.0f * dv;   // x2 omitted: same ordering
      const int kg = t * KB + krow;
      if (sq < t4v) {
        if (sq < t3v) { t4v = t3v; i4 = i3;
          if (sq < t2v) { t3v = t2v; i3 = i2;
            if (sq < t1v) { t2v = t1v; i2 = i1;
              if (sq < t0v) { t1v = t0v; i1 = i0; t0v = sq; i0 = kg; }
              else          { t1v = sq; i1 = kg; } }
            else { t2v = sq; i2 = kg; } }
          else { t3v = sq; i3 = kg; } }
        else { t4v = sq; i4 = kg; }
      }
    }
  }

  __syncthreads();
  if (s < 8) {                            // lanes s>=8 hold identical dup lists
    const int fl = w * 8 + s;
    candSq[fl][g][0] = t0v; candSq[fl][g][1] = t1v; candSq[fl][g][2] = t2v;
    candSq[fl][g][3] = t3v; candSq[fl][g][4] = t4v;
    candIx[fl][g][0] = i0; candIx[fl][g][1] = i1; candIx[fl][g][2] = i2;
    candIx[fl][g][3] = i3; candIx[fl][g][4] = i4;
  }
  __syncthreads();

  if (tid < MBF) {                        // merge 4x5 -> top5, softmax
    float bs[TK]; int bi[TK];
#pragma unroll
    for (int sel = 0; sel < TK; ++sel) {
      float mv = FMAXV; int mg = 0, mc = 0;
      for (int g2 = 0; g2 < 4; ++g2)
        for (int c = 0; c < TK; ++c) {
          const float v = candSq[tid][g2][c];
          if (v < mv) { mv = v; mg = g2; mc = c; }
        }
      bs[sel] = mv; bi[sel] = candIx[tid][mg][mc];
      candSq[tid][mg][mc] = FMAXV;
    }
    const float x2 = sX2[tid];
    float dd[TK], ee[TK], sum = 0.f;
#pragma unroll
    for (int i = 0; i < TK; ++i) dd[i] = sqrtf(fmaxf(x2 + bs[i], 0.0f));
#pragma unroll
    for (int i = 0; i < TK; ++i) { ee[i] = expf(dd[0] - dd[i]); sum += ee[i]; }
    const float inv = 1.0f / sum;
#pragma unroll
    for (int i = 0; i < TK; ++i) { topP[tid][i] = ee[i] * inv; topI[tid][i] = bi[i]; }
    sAtt[tid] = A[b * NFEAT + fbase + tid];
  }
  __syncthreads();

  // scatter: 160 rows of 256 floats; one wave-task per row
  for (int task = w; task < MBF * TK; task += 4) {
    const int f = task & 31, slot = task >> 5;
    const int kidx = topI[f][slot];
    const float p = topP[f][slot];
    const float coef = sAtt[f] * p;
    const float4 xr = *(const float4*)(F + ((size_t)(b * NFEAT + fbase + f)) * DDIM + l * 4);
    const float4 cr = *(const float4*)(C + (size_t)kidx * DDIM + l * 4);
    float* o = outG + ((size_t)(b * KCENT) + kidx) * DDIM + l * 4;
    __hip_atomic_fetch_add(o + 0, coef * (xr.x - cr.x), __ATOMIC_RELAXED, __HIP_MEMORY_SCOPE_AGENT);
    __hip_atomic_fetch_add(o + 1, coef * (xr.y - cr.y), __ATOMIC_RELAXED, __HIP_MEMORY_SCOPE_AGENT);
    __hip_atomic_fetch_add(o + 2, coef * (xr.z - cr.z), __ATOMIC_RELAXED, __HIP_MEMORY_SCOPE_AGENT);
    __hip_atomic_fetch_add(o + 3, coef * (xr.w - cr.w), __ATOMIC_RELAXED, __HIP_MEMORY_SCOPE_AGENT);
    if (l == 0) atomicMax((unsigned int*)(outW + b * KCENT + kidx), __float_as_uint(p));
  }
}

// ---- grouped = dense / (||dense|| + eps) -----------------------------------
__global__ __launch_bounds__(256) void k_norm(float* __restrict__ G) {
  const int w = threadIdx.x >> 6, l = threadIdx.x & 63;
  const size_t row = (size_t)blockIdx.x * 4 + w;
  float* p = G + row * DDIM + l * 4;
  float4 v = *(const float4*)p;
  float ss = v.x*v.x + v.y*v.y + v.z*v.z + v.w*v.w;
  ss = red16(ss);
  ss += __shfl_xor(ss, 16);
  ss += __shfl_xor(ss, 32);
  const float sc = 1.0f / (sqrtf(ss) + 1e-6f);
  v.x *= sc; v.y *= sc; v.z *= sc; v.w *= sc;
  *(float4*)p = v;
}

extern "C" void kernel_launch(void* const* d_in, const int* in_sizes, int n_in,
                              void* d_out, int out_size, void* d_ws, size_t ws_size,
                              hipStream_t stream) {
  const float* F = (const float*)d_in[0];   // [B,N,D]
  const float* A = (const float*)d_in[1];   // [B,N,1]
  const float* C = (const float*)d_in[2];   // [K,D]
  float* outG = (float*)d_out;                               // [B,K,D]
  float* outW = outG + (size_t)BDIM * KCENT * DDIM;          // [B,K]
  float* c2  = (float*)d_ws;                                 // [K]

  hipMemsetAsync(d_out, 0, (size_t)out_size * sizeof(float), stream);
  k_c2 <<<KCENT / 4, 256, 0, stream>>>(C, c2);
  k_main<<<BDIM * 64, 256, 0, stream>>>(F, A, C, c2, outG, outW);
  k_norm<<<(BDIM * KCENT) / 4, 256, 0, stream>>>(outG);
}

// Round 2
// 421.165 us; speedup vs baseline: 4.7547x; 4.7547x over previous
//
#include <hip/hip_runtime.h>
#include <hip/hip_bf16.h>
#include <math.h>

#define BDIM  4
#define NFEAT 2048
#define DDIM  256
#define KCENT 16384
#define TK    5
#define NCB   4                 // centroid column splits (one per XCD mod 4)
#define CBSZ  (KCENT / NCB)     // 4096
#define KB    128               // centroids per LDS tile
#define NT    (CBSZ / KB)       // 32 tiles
#define FB    128               // features per block
#define INFF  (__builtin_inff())

typedef __attribute__((ext_vector_type(4))) float  f32x4;
typedef __attribute__((ext_vector_type(8))) short  short8v;   // 8 bf16 = 4 VGPR

static __device__ __forceinline__ short f2bf(float x) {
  __hip_bfloat16 h = __float2bfloat16(x);
  return __builtin_bit_cast(short, h);
}

static __device__ __forceinline__ float wsum(float v) {
  v += __shfl_xor(v, 1);  v += __shfl_xor(v, 2);  v += __shfl_xor(v, 4);
  v += __shfl_xor(v, 8);  v += __shfl_xor(v, 16); v += __shfl_xor(v, 32);
  return v;
}

// ---- fp32 -> bf16 bulk convert (8 elems/thread) ----------------------------
__global__ __launch_bounds__(256) void k_cvt(const float* __restrict__ src,
                                             short* __restrict__ dst, int n8) {
  const int i = blockIdx.x * 256 + threadIdx.x;
  if (i >= n8) return;
  const float4* s = (const float4*)src + (size_t)i * 2;
  const float4 a = s[0], b = s[1];
  short8v o;
  o[0] = f2bf(a.x); o[1] = f2bf(a.y); o[2] = f2bf(a.z); o[3] = f2bf(a.w);
  o[4] = f2bf(b.x); o[5] = f2bf(b.y); o[6] = f2bf(b.z); o[7] = f2bf(b.w);
  ((short8v*)dst)[i] = o;
}

// ---- c2[k] = sum(C[k,:]^2) exact fp32 --------------------------------------
__global__ __launch_bounds__(256) void k_c2(const float* __restrict__ C, float* __restrict__ c2) {
  const int w = threadIdx.x >> 6, l = threadIdx.x & 63;
  const int row = blockIdx.x * 4 + w;
  const float4 v = *(const float4*)(C + (size_t)row * DDIM + l * 4);
  const float ss = wsum(v.x*v.x + v.y*v.y + v.z*v.z + v.w*v.w);
  if (l == 0) c2[row] = ss;
}

// ---- bf16 MFMA distance pass + fused top-5 -> approx top-8 per (feat, cb) --
__global__ __launch_bounds__(512, 2) void k_main(
    const short* __restrict__ Xbf, const short* __restrict__ Cbf,
    const float* __restrict__ c2g, uint2* __restrict__ cand)
{
  __shared__ short sC[2][KB * DDIM];   // 2 x 64 KB, dbuf centroid tiles (buf1 = X tile first)
  __shared__ float sC2[2][KB];

  const int tid = threadIdx.x;
  const int l = tid & 63, w = tid >> 6;
  const int wm = w & 3, wn = w >> 2;        // wave grid: 4 over cents x 2 over feats
  const int lrow = l & 15, lk = l >> 4;
  const int cb = blockIdx.x & 3, fb = blockIdx.x >> 2;
  const size_t coff = (size_t)cb * CBSZ * DDIM;
  const int fbase = fb * FB;

  // stage 64 KB tile: linear LDS dest, XOR-swizzled global source (T2 via m173)
  auto stage = [&](const short* gsrc, int buf) {
#pragma unroll
    for (int r = 0; r < 8; ++r) {
      const int L = r * 8192 + tid * 16;
      const int row = L >> 9;
      const int kb = (L & 511) ^ ((row & 7) << 4);
      __builtin_amdgcn_global_load_lds(
          (const __attribute__((address_space(1))) void*)((const char*)gsrc + row * 512 + kb),
          (__attribute__((address_space(3))) void*)((char*)&sC[buf][0] + L), 16, 0, 0);
    }
  };

  stage(Xbf + (size_t)fbase * DDIM, 1);
  stage(Cbf + coff, 0);
  if (tid < KB) sC2[0][tid] = c2g[cb * CBSZ + tid];
  __syncthreads();

  // B-frags (features) resident in registers: lane holds X[wn*64+nf*16+lrow][k8]
  short8v bfr[4][8];
#pragma unroll
  for (int nf = 0; nf < 4; ++nf) {
    const int row = wn * 64 + nf * 16 + lrow;
    const char* rp = (const char*)&sC[1][0] + row * 512;
    const int sw = (row & 7) << 4;
#pragma unroll
    for (int kk = 0; kk < 8; ++kk)
      bfr[nf][kk] = *(const short8v*)(rp + ((kk * 64 + lk * 16) ^ sw));
  }
  __syncthreads();   // sC[1] free for staging

  float lv[4][5]; int li[4][5];
#pragma unroll
  for (int nf = 0; nf < 4; ++nf)
#pragma unroll
    for (int j = 0; j < 5; ++j) { lv[nf][j] = INFF; li[nf][j] = 0; }

  for (int t = 0; t < NT; ++t) {
    const int buf = t & 1;
    if (t + 1 < NT) {
      stage(Cbf + coff + (size_t)(t + 1) * KB * DDIM, buf ^ 1);
      if (tid < KB) sC2[buf ^ 1][tid] = c2g[cb * CBSZ + (t + 1) * KB + tid];
    }
    const f32x4 z = {0.f, 0.f, 0.f, 0.f};
    f32x4 acc[2][4];
#pragma unroll
    for (int mf = 0; mf < 2; ++mf)
#pragma unroll
      for (int nf = 0; nf < 4; ++nf) acc[mf][nf] = z;

    const char* base = (const char*)&sC[buf][0];
    const int row0 = wm * 32 + lrow;
    const char* rp0 = base + row0 * 512;
    const char* rp1 = rp0 + 16 * 512;
    const int sw = (row0 & 7) << 4;          // row0+16 has same (row&7)
#pragma unroll
    for (int kk = 0; kk < 8; ++kk) {
      const int ko = (kk * 64 + lk * 16) ^ sw;
      const short8v a0 = *(const short8v*)(rp0 + ko);
      const short8v a1 = *(const short8v*)(rp1 + ko);
#pragma unroll
      for (int nf = 0; nf < 4; ++nf) {
        acc[0][nf] = __builtin_amdgcn_mfma_f32_16x16x32_bf16(a0, bfr[nf][kk], acc[0][nf], 0, 0, 0);
        acc[1][nf] = __builtin_amdgcn_mfma_f32_16x16x32_bf16(a1, bfr[nf][kk], acc[1][nf], 0, 0, 0);
      }
    }
    const f32x4 cc0 = *(const f32x4*)&sC2[buf][wm * 32 + lk * 4];
    const f32x4 cc1 = *(const f32x4*)&sC2[buf][wm * 32 + 16 + lk * 4];
    const int cbase0 = cb * CBSZ + t * KB + wm * 32 + lk * 4;
#pragma unroll
    for (int mf = 0; mf < 2; ++mf) {
#pragma unroll
      for (int r = 0; r < 4; ++r) {
        const float c2v = mf ? cc1[r] : cc0[r];
        const int cix = cbase0 + mf * 16 + r;
#pragma unroll
        for (int nf = 0; nf < 4; ++nf) {
          const float sq = fmaf(-2.0f, acc[mf][nf][r], c2v);
          if (sq < lv[nf][4]) {                       // rare after warm-up
            const bool b3 = sq < lv[nf][3], b2 = sq < lv[nf][2];
            const bool b1 = sq < lv[nf][1], b0 = sq < lv[nf][0];
            lv[nf][4] = b3 ? lv[nf][3] : sq;  li[nf][4] = b3 ? li[nf][3] : cix;
            if (b3) { lv[nf][3] = b2 ? lv[nf][2] : sq; li[nf][3] = b2 ? li[nf][2] : cix; }
            if (b2) { lv[nf][2] = b1 ? lv[nf][1] : sq; li[nf][2] = b1 ? li[nf][1] : cix; }
            if (b1) { lv[nf][1] = b0 ? lv[nf][0] : sq; li[nf][1] = b0 ? li[nf][0] : cix; }
            if (b0) { lv[nf][0] = sq;          li[nf][0] = cix; }
          }
        }
      }
    }
    __syncthreads();
  }

  // ---- merge 4 waves x 4 lane-groups (80 cands/feature) -> top-8 -> ws -----
  float* dsq  = (float*)&sC[0][0];            // 10240 floats (40 KB)
  int*   didx = (int*)&sC[0][0] + 10240;      // next 40 KB
#pragma unroll
  for (int nf = 0; nf < 4; ++nf) {
    const int fl6 = nf * 16 + lrow;
    const int eb = (((wn * 4 + wm) * 4 + lk) * 64 + fl6) * 5;
#pragma unroll
    for (int j = 0; j < 5; ++j) { dsq[eb + j] = lv[nf][j]; didx[eb + j] = li[nf][j]; }
  }
  __syncthreads();
  if (tid < FB) {
    const int wn2 = tid >> 6, fl6 = tid & 63;
    float t8v[8]; int t8i[8];
#pragma unroll
    for (int j = 0; j < 8; ++j) { t8v[j] = INFF; t8i[j] = 0; }
    for (int g = 0; g < 16; ++g) {
      const int eb = ((wn2 * 16 + g) * 64 + fl6) * 5;
#pragma unroll
      for (int j = 0; j < 5; ++j) {
        const float v = dsq[eb + j]; const int ix = didx[eb + j];
        if (v < t8v[7]) {
          const bool c6 = v < t8v[6], c5 = v < t8v[5], c4 = v < t8v[4],
                     c3 = v < t8v[3], c2b = v < t8v[2], c1 = v < t8v[1], c0 = v < t8v[0];
          t8v[7] = c6 ? t8v[6] : v;  t8i[7] = c6 ? t8i[6] : ix;
          if (c6)  { t8v[6] = c5 ? t8v[5] : v;  t8i[6] = c5 ? t8i[5] : ix; }
          if (c5)  { t8v[5] = c4 ? t8v[4] : v;  t8i[5] = c4 ? t8i[4] : ix; }
          if (c4)  { t8v[4] = c3 ? t8v[3] : v;  t8i[4] = c3 ? t8i[3] : ix; }
          if (c3)  { t8v[3] = c2b ? t8v[2] : v; t8i[3] = c2b ? t8i[2] : ix; }
          if (c2b) { t8v[2] = c1 ? t8v[1] : v;  t8i[2] = c1 ? t8i[1] : ix; }
          if (c1)  { t8v[1] = c0 ? t8v[0] : v;  t8i[1] = c0 ? t8i[0] : ix; }
          if (c0)  { t8v[0] = v;                t8i[0] = ix; }
        }
      }
    }
    uint2* cp = cand + ((size_t)(fbase + tid) * NCB + cb) * 8;
#pragma unroll
    for (int j = 0; j < 8; ++j) cp[j] = make_uint2(__float_as_uint(t8v[j]), (unsigned)t8i[j]);
  }
}

// ---- exact fp32 rescore of 32 cands -> top-5, softmax, scatter -------------
__global__ __launch_bounds__(256) void k_post(
    const float* __restrict__ F, const float* __restrict__ A,
    const float* __restrict__ C, const float* __restrict__ c2g,
    const uint2* __restrict__ cand, float* __restrict__ outG, float* __restrict__ outW)
{
  __shared__ int sIdx[4][32];
  const int l = threadIdx.x & 63, w = threadIdx.x >> 6;
  const int f = blockIdx.x * 4 + w;
  const int b = f >> 11;

  const float4 xv = *(const float4*)(F + (size_t)f * DDIM + l * 4);
  const float x2 = wsum(xv.x*xv.x + xv.y*xv.y + xv.z*xv.z + xv.w*xv.w);
  if (l < 32) sIdx[w][l] = (int)cand[(size_t)f * 32 + l].y;   // same-wave ds RAW: compiler waits lgkmcnt

  float msq = INFF; int midx = 0;
#pragma unroll 4
  for (int j = 0; j < 32; ++j) {
    const int ci = sIdx[w][j];
    const float4 cv = *(const float4*)(C + (size_t)ci * DDIM + l * 4);
    const float d = wsum(xv.x*cv.x + xv.y*cv.y + xv.z*cv.z + xv.w*cv.w);
    const float sq = fmaxf(fmaf(-2.0f, d, x2 + c2g[ci]), 0.0f);
    if (l == j) { msq = sq; midx = ci; }
  }

  unsigned long long key = (((unsigned long long)__float_as_uint(msq)) << 32) | (unsigned)l;
  float ssq[TK]; int sidx[TK];
#pragma unroll
  for (int s = 0; s < TK; ++s) {
    unsigned long long m = key;
#pragma unroll
    for (int d = 1; d < 64; d <<= 1) {
      const unsigned long long o = __shfl_xor(m, d);
      m = o < m ? o : m;
    }
    const int wl = (int)(m & 63);
    ssq[s]  = __uint_as_float((unsigned)(m >> 32));
    sidx[s] = __shfl(midx, wl);
    if (l == wl) key = ~0ull;
  }

  float ee[TK], sum = 0.f;
  const float d0 = sqrtf(ssq[0]);
#pragma unroll
  for (int s = 0; s < TK; ++s) { ee[s] = expf(d0 - sqrtf(ssq[s])); sum += ee[s]; }
  const float inv = 1.0f / sum;
  const float att = A[f];

#pragma unroll
  for (int s = 0; s < TK; ++s) {
    const float p = ee[s] * inv;
    const int k = sidx[s];
    const float4 cv = *(const float4*)(C + (size_t)k * DDIM + l * 4);
    const float coef = att * p;
    float* o = outG + ((size_t)b * KCENT + k) * DDIM + l * 4;
    __hip_atomic_fetch_add(o + 0, coef * (xv.x - cv.x), __ATOMIC_RELAXED, __HIP_MEMORY_SCOPE_AGENT);
    __hip_atomic_fetch_add(o + 1, coef * (xv.y - cv.y), __ATOMIC_RELAXED, __HIP_MEMORY_SCOPE_AGENT);
    __hip_atomic_fetch_add(o + 2, coef * (xv.z - cv.z), __ATOMIC_RELAXED, __HIP_MEMORY_SCOPE_AGENT);
    __hip_atomic_fetch_add(o + 3, coef * (xv.w - cv.w), __ATOMIC_RELAXED, __HIP_MEMORY_SCOPE_AGENT);
    if (l == 0) atomicMax((unsigned*)&outW[(size_t)b * KCENT + k], __float_as_uint(p));
  }
}

// ---- grouped = dense / (||dense|| + eps) -----------------------------------
__global__ __launch_bounds__(256) void k_norm(float* __restrict__ G) {
  const int w = threadIdx.x >> 6, l = threadIdx.x & 63;
  const size_t row = (size_t)blockIdx.x * 4 + w;
  float* p = G + row * DDIM + l * 4;
  float4 v = *(const float4*)p;
  const float ss = wsum(v.x*v.x + v.y*v.y + v.z*v.z + v.w*v.w);
  const float sc = 1.0f / (sqrtf(ss) + 1e-6f);
  v.x *= sc; v.y *= sc; v.z *= sc; v.w *= sc;
  *(float4*)p = v;
}

extern "C" void kernel_launch(void* const* d_in, const int* in_sizes, int n_in,
                              void* d_out, int out_size, void* d_ws, size_t ws_size,
                              hipStream_t stream) {
  const float* F = (const float*)d_in[0];   // [B,N,D]
  const float* A = (const float*)d_in[1];   // [B,N,1]
  const float* C = (const float*)d_in[2];   // [K,D]
  float* outG = (float*)d_out;
  float* outW = outG + (size_t)BDIM * KCENT * DDIM;

  char* ws = (char*)d_ws;
  short* Xbf = (short*)ws;                         // 4 MB
  short* Cbf = (short*)(ws + (4u << 20));          // 8 MB
  float* c2  = (float*)(ws + (12u << 20));         // 64 KB
  uint2* cand = (uint2*)(ws + (13u << 20));        // 2 MB: [8192][4][8]

  hipMemsetAsync(d_out, 0, (size_t)out_size * sizeof(float), stream);
  k_cvt <<<(BDIM * NFEAT * DDIM / 8 + 255) / 256, 256, 0, stream>>>(F, Xbf, BDIM * NFEAT * DDIM / 8);
  k_cvt <<<(KCENT * DDIM / 8 + 255) / 256, 256, 0, stream>>>(C, Cbf, KCENT * DDIM / 8);
  k_c2  <<<KCENT / 4, 256, 0, stream>>>(C, c2);
  k_main<<<(BDIM * NFEAT / FB) * NCB, 512, 0, stream>>>(Xbf, Cbf, c2, cand);
  k_post<<<BDIM * NFEAT / 4, 256, 0, stream>>>(F, A, C, c2, cand, outG, outW);
  k_norm<<<(BDIM * KCENT) / 4, 256, 0, stream>>>(outG);
}

// Round 3
// 336.323 us; speedup vs baseline: 5.9542x; 1.2523x over previous
//
#include <hip/hip_runtime.h>
#include <hip/hip_bf16.h>
#include <math.h>

#define BDIM  4
#define NFEAT 2048
#define DDIM  256
#define KCENT 16384
#define TK    5
#define NCB   4
#define CBSZ  (KCENT / NCB)   // 4096
#define KB    128             // centroids per tile
#define NT    (CBSZ / KB)     // 32
#define FB    128             // features per block
#define RESC  12              // exactly-rescored candidates per feature
#define INFF  (__builtin_inff())

typedef __attribute__((ext_vector_type(4))) float  f32x4;
typedef __attribute__((ext_vector_type(8))) short  short8v;
typedef unsigned long long u64;

static __device__ __forceinline__ short f2bf(float x) {
  __hip_bfloat16 h = __float2bfloat16(x);
  return __builtin_bit_cast(short, h);
}

static __device__ __forceinline__ float wsum(float v) {
  v += __shfl_xor(v, 1);  v += __shfl_xor(v, 2);  v += __shfl_xor(v, 4);
  v += __shfl_xor(v, 8);  v += __shfl_xor(v, 16); v += __shfl_xor(v, 32);
  return v;
}

// ---- fp32 -> bf16 bulk convert ---------------------------------------------
__global__ __launch_bounds__(256) void k_cvt(const float* __restrict__ src,
                                             short* __restrict__ dst, int n8) {
  const int i = blockIdx.x * 256 + threadIdx.x;
  if (i >= n8) return;
  const float4* s = (const float4*)src + (size_t)i * 2;
  const float4 a = s[0], b = s[1];
  short8v o;
  o[0] = f2bf(a.x); o[1] = f2bf(a.y); o[2] = f2bf(a.z); o[3] = f2bf(a.w);
  o[4] = f2bf(b.x); o[5] = f2bf(b.y); o[6] = f2bf(b.z); o[7] = f2bf(b.w);
  ((short8v*)dst)[i] = o;
}

// ---- c2[k] = sum(C[k,:]^2) exact fp32 --------------------------------------
__global__ __launch_bounds__(256) void k_c2(const float* __restrict__ C, float* __restrict__ c2) {
  const int w = threadIdx.x >> 6, l = threadIdx.x & 63;
  const int row = blockIdx.x * 4 + w;
  const float4 v = *(const float4*)(C + (size_t)row * DDIM + l * 4);
  const float ss = wsum(v.x*v.x + v.y*v.y + v.z*v.z + v.w*v.w);
  if (l == 0) c2[row] = ss;
}

// ---- bf16 MFMA distance pass, packed-key top-5, per-feature top-8 ----------
// LDS tile layout (fragment-major, conflict-free):
//   L = g*8192 + kk*1024 + c*16,  c = kc*16 + row16
//   holds A[g*16+row16][kk*32+kc*8 .. +8] (bf16)
// ds_read for MFMA frag: base + l*16 (lane-linear), kk*1024 as imm offset.
// global_load_lds: dest linear (r*8192 + tid*16); source offset per thread:
//   poff = (tid&15)*512 + (tid>>6)*64 + ((tid>>4)&3)*16   (+ r*8192)
__global__ __launch_bounds__(512, 2) void k_main(
    const short* __restrict__ Xbf, const short* __restrict__ Cbf,
    const float* __restrict__ c2g, uint2* __restrict__ cand)
{
  __shared__ short sC[2][KB * DDIM];   // 2 x 64 KB
  __shared__ float sC2[2][KB];

  const int tid = threadIdx.x;
  const int l = tid & 63, w = tid >> 6;
  const int wm = w & 3, wn = w >> 2;
  const int lrow = l & 15, lk = l >> 4;
  const int cb = blockIdx.x & (NCB - 1), fb = blockIdx.x / NCB;
  const int fbase = fb * FB;
  const size_t coffB = (size_t)cb * CBSZ * (DDIM * 2);

  const int poff = (tid & 15) * 512 + (tid >> 6) * 64 + ((tid >> 4) & 3) * 16;

  auto stage = [&](const char* gsrcB, int buf) {
#pragma unroll
    for (int r = 0; r < 8; ++r) {
      __builtin_amdgcn_global_load_lds(
          (const __attribute__((address_space(1))) void*)(gsrcB + r * 8192 + poff),
          (__attribute__((address_space(3))) void*)((char*)&sC[buf][0] + r * 8192 + tid * 16),
          16, 0, 0);
    }
  };

  stage((const char*)Xbf + (size_t)fbase * 512, 1);
  stage((const char*)Cbf + coffB, 0);
  if (tid < KB) sC2[0][tid] = c2g[cb * CBSZ + tid] + 1024.0f;
  __syncthreads();

  // feature fragments -> registers (feature = wn*64 + nf*16 + lrow)
  short8v bfr[4][8];
#pragma unroll
  for (int nf = 0; nf < 4; ++nf) {
    const char* bp = (const char*)&sC[1][0] + (wn * 4 + nf) * 8192 + l * 16;
#pragma unroll
    for (int kk = 0; kk < 8; ++kk)
      bfr[nf][kk] = *(const short8v*)(bp + kk * 1024);
  }
  __syncthreads();   // buf1 free for staging

  const char* a0b0 = (const char*)&sC[0][0] + (wm * 2 + 0) * 8192 + l * 16;
  const char* a1b0 = (const char*)&sC[0][0] + (wm * 2 + 1) * 8192 + l * 16;
  const char* a0b1 = (const char*)&sC[1][0] + (wm * 2 + 0) * 8192 + l * 16;
  const char* a1b1 = (const char*)&sC[1][0] + (wm * 2 + 1) * 8192 + l * 16;

  unsigned kv[4][5];   // packed keys, ascending; low 8 bits = q = t*8+mf*4+r
#pragma unroll
  for (int nf = 0; nf < 4; ++nf)
#pragma unroll
    for (int j = 0; j < 5; ++j) kv[nf][j] = 0xFFFFFFFFu;

  for (int t = 0; t < NT; ++t) {
    const int buf = t & 1;
    if (t + 1 < NT) {
      stage((const char*)Cbf + coffB + (size_t)(t + 1) * (KB * 512), buf ^ 1);
      if (tid < KB) sC2[buf ^ 1][tid] = c2g[cb * CBSZ + (t + 1) * KB + tid] + 1024.0f;
    }

    f32x4 acc[2][4];
    const f32x4 z = {0.f, 0.f, 0.f, 0.f};
#pragma unroll
    for (int mf = 0; mf < 2; ++mf)
#pragma unroll
      for (int nf = 0; nf < 4; ++nf) acc[mf][nf] = z;

    const char* ap0 = buf ? a0b1 : a0b0;
    const char* ap1 = buf ? a1b1 : a1b0;
#pragma unroll
    for (int kk = 0; kk < 8; ++kk) {
      const short8v a0 = *(const short8v*)(ap0 + kk * 1024);
      const short8v a1 = *(const short8v*)(ap1 + kk * 1024);
#pragma unroll
      for (int nf = 0; nf < 4; ++nf) {
        acc[0][nf] = __builtin_amdgcn_mfma_f32_16x16x32_bf16(a0, bfr[nf][kk], acc[0][nf], 0, 0, 0);
        acc[1][nf] = __builtin_amdgcn_mfma_f32_16x16x32_bf16(a1, bfr[nf][kk], acc[1][nf], 0, 0, 0);
      }
    }

    const f32x4 cb0 = *(const f32x4*)&sC2[buf][wm * 32 + lk * 4];
    const f32x4 cb1 = *(const f32x4*)&sC2[buf][wm * 32 + 16 + lk * 4];
#pragma unroll
    for (int mf = 0; mf < 2; ++mf)
#pragma unroll
      for (int r = 0; r < 4; ++r) {
        const float c2v = mf ? cb1[r] : cb0[r];
        const unsigned q = (unsigned)(t * 8 + mf * 4 + r);
#pragma unroll
        for (int nf = 0; nf < 4; ++nf) {
          const float sqb = fmaf(-2.0f, acc[mf][nf][r], c2v);   // biased, ordering-exact
          unsigned x = (__float_as_uint(sqb) & 0xFFFFFF00u) | q;
#define INS(S) { const unsigned lo = kv[nf][S] < x ? kv[nf][S] : x; \
                 x = kv[nf][S] < x ? x : kv[nf][S]; kv[nf][S] = lo; }
          INS(0) INS(1) INS(2) INS(3)
          kv[nf][4] = kv[nf][4] < x ? kv[nf][4] : x;
#undef INS
        }
      }
    __syncthreads();
  }

  // dump per-(lane,feature) lists: [128 feats][16 slots][5], stride 81 (pad)
  unsigned* mb = (unsigned*)&sC[0][0];
#pragma unroll
  for (int nf = 0; nf < 4; ++nf) {
    const int fl = wn * 64 + nf * 16 + lrow;
    const int s = wm * 4 + lk;
#pragma unroll
    for (int j = 0; j < 5; ++j) mb[fl * 81 + s * 5 + j] = kv[nf][j];
  }
  __syncthreads();

  if (tid < FB) {
    unsigned bv[8], bi[8];
#pragma unroll
    for (int j = 0; j < 8; ++j) { bv[j] = 0xFFFFFFFFu; bi[j] = 0; }
    const unsigned* row = mb + tid * 81;
    for (int s = 0; s < 16; ++s) {
      const unsigned aux = (unsigned)(cb * CBSZ + (s >> 2) * 32 + (s & 3) * 4);
#pragma unroll
      for (int j = 0; j < 5; ++j) {
        const unsigned v = row[s * 5 + j];
        const unsigned q = v & 255u;
        const unsigned ci = aux + (q >> 3) * 128 + ((q >> 2) & 1u) * 16 + (q & 3u);
        const bool s0 = v < bv[0], s1 = v < bv[1], s2 = v < bv[2], s3 = v < bv[3],
                   s4 = v < bv[4], s5 = v < bv[5], s6 = v < bv[6], s7 = v < bv[7];
        bv[7] = s6 ? bv[6] : (s7 ? v : bv[7]);  bi[7] = s6 ? bi[6] : (s7 ? ci : bi[7]);
        bv[6] = s5 ? bv[5] : (s6 ? v : bv[6]);  bi[6] = s5 ? bi[5] : (s6 ? ci : bi[6]);
        bv[5] = s4 ? bv[4] : (s5 ? v : bv[5]);  bi[5] = s4 ? bi[4] : (s5 ? ci : bi[5]);
        bv[4] = s3 ? bv[3] : (s4 ? v : bv[4]);  bi[4] = s3 ? bi[3] : (s4 ? ci : bi[4]);
        bv[3] = s2 ? bv[2] : (s3 ? v : bv[3]);  bi[3] = s2 ? bi[2] : (s3 ? ci : bi[3]);
        bv[2] = s1 ? bv[1] : (s2 ? v : bv[2]);  bi[2] = s1 ? bi[1] : (s2 ? ci : bi[2]);
        bv[1] = s0 ? bv[0] : (s1 ? v : bv[1]);  bi[1] = s0 ? bi[0] : (s1 ? ci : bi[1]);
        bv[0] = s0 ? v : bv[0];                 bi[0] = s0 ? ci : bi[0];
      }
    }
    uint2* cp = cand + ((size_t)(fbase + tid) * NCB + cb) * 8;
#pragma unroll
    for (int j = 0; j < 8; ++j) cp[j] = make_uint2(bv[j], bi[j]);
  }
}

// ---- exact fp32 rescore of approx-top-12 -> top-5, softmax, scatter --------
__global__ __launch_bounds__(256) void k_post(
    const float* __restrict__ F, const float* __restrict__ A,
    const float* __restrict__ C, const float* __restrict__ c2g,
    const uint2* __restrict__ cand, float* __restrict__ outG, float* __restrict__ outW)
{
  const int l = threadIdx.x & 63, w = threadIdx.x >> 6;
  const int f = blockIdx.x * 4 + w;
  const int b = f >> 11;

  const float4 xv = *(const float4*)(F + (size_t)f * DDIM + l * 4);
  const float x2 = wsum(xv.x*xv.x + xv.y*xv.y + xv.z*xv.z + xv.w*xv.w);

  uint2 e = make_uint2(0xFFFFFFFFu, 0u);
  if (l < 32) e = cand[(size_t)f * 32 + l];
  u64 key = ((u64)e.x << 6) | (unsigned)l;
  if (l >= 32) key = ~0ull;

  float msq = INFF; int midx = 0;
#pragma unroll
  for (int it = 0; it < RESC; ++it) {
    u64 m = key;
#pragma unroll
    for (int d = 1; d < 64; d <<= 1) { const u64 o = __shfl_xor(m, d); m = o < m ? o : m; }
    const int wl = (int)(m & 63u);
    const int ci = __shfl((int)e.y, wl);
    if (l == wl) key = ~0ull;
    const float4 cv = *(const float4*)(C + (size_t)ci * DDIM + l * 4);
    const float d2 = wsum(xv.x*cv.x + xv.y*cv.y + xv.z*cv.z + xv.w*cv.w);
    const float sq = fmaxf(fmaf(-2.0f, d2, x2 + c2g[ci]), 0.0f);
    if (l == it) { msq = sq; midx = ci; }
  }

  u64 k2 = ((u64)__float_as_uint(msq) << 32) | (unsigned)l;
  float ssq[TK]; int sidx[TK];
#pragma unroll
  for (int s = 0; s < TK; ++s) {
    u64 m = k2;
#pragma unroll
    for (int d = 1; d < 64; d <<= 1) { const u64 o = __shfl_xor(m, d); m = o < m ? o : m; }
    const int wl = (int)(m & 0xFFFFFFFFull);
    ssq[s] = __uint_as_float((unsigned)(m >> 32));
    sidx[s] = __shfl(midx, wl);
    if (l == wl) k2 = ~0ull;
  }

  float ee[TK], sum = 0.f;
  const float d0 = sqrtf(ssq[0]);
#pragma unroll
  for (int s = 0; s < TK; ++s) { ee[s] = expf(d0 - sqrtf(ssq[s])); sum += ee[s]; }
  const float inv = 1.0f / sum;
  const float att = A[f];

#pragma unroll
  for (int s = 0; s < TK; ++s) {
    const float p = ee[s] * inv;
    const int k = sidx[s];
    const float4 cv = *(const float4*)(C + (size_t)k * DDIM + l * 4);
    const float coef = att * p;
    float* o = outG + ((size_t)b * KCENT + k) * DDIM + l * 4;
    __hip_atomic_fetch_add(o + 0, coef * (xv.x - cv.x), __ATOMIC_RELAXED, __HIP_MEMORY_SCOPE_AGENT);
    __hip_atomic_fetch_add(o + 1, coef * (xv.y - cv.y), __ATOMIC_RELAXED, __HIP_MEMORY_SCOPE_AGENT);
    __hip_atomic_fetch_add(o + 2, coef * (xv.z - cv.z), __ATOMIC_RELAXED, __HIP_MEMORY_SCOPE_AGENT);
    __hip_atomic_fetch_add(o + 3, coef * (xv.w - cv.w), __ATOMIC_RELAXED, __HIP_MEMORY_SCOPE_AGENT);
    if (l == 0) atomicMax((unsigned*)&outW[(size_t)b * KCENT + k], __float_as_uint(p));
  }
}

// ---- grouped = dense / (||dense|| + eps) -----------------------------------
__global__ __launch_bounds__(256) void k_norm(float* __restrict__ G) {
  const int w = threadIdx.x >> 6, l = threadIdx.x & 63;
  const size_t row = (size_t)blockIdx.x * 4 + w;
  float* p = G + row * DDIM + l * 4;
  float4 v = *(const float4*)p;
  const float ss = wsum(v.x*v.x + v.y*v.y + v.z*v.z + v.w*v.w);
  const float sc = 1.0f / (sqrtf(ss) + 1e-6f);
  v.x *= sc; v.y *= sc; v.z *= sc; v.w *= sc;
  *(float4*)p = v;
}

extern "C" void kernel_launch(void* const* d_in, const int* in_sizes, int n_in,
                              void* d_out, int out_size, void* d_ws, size_t ws_size,
                              hipStream_t stream) {
  const float* F = (const float*)d_in[0];
  const float* A = (const float*)d_in[1];
  const float* C = (const float*)d_in[2];
  float* outG = (float*)d_out;
  float* outW = outG + (size_t)BDIM * KCENT * DDIM;

  char* ws = (char*)d_ws;
  short* Xbf  = (short*)ws;                        // 4 MB
  short* Cbf  = (short*)(ws + (4u << 20));         // 8 MB
  float* c2   = (float*)(ws + (12u << 20));        // 64 KB
  uint2* cand = (uint2*)(ws + (13u << 20));        // 2 MB: [8192][4][8]

  hipMemsetAsync(d_out, 0, (size_t)out_size * sizeof(float), stream);
  k_cvt <<<(BDIM * NFEAT * DDIM / 8 + 255) / 256, 256, 0, stream>>>(F, Xbf, BDIM * NFEAT * DDIM / 8);
  k_cvt <<<(KCENT * DDIM / 8 + 255) / 256, 256, 0, stream>>>(C, Cbf, KCENT * DDIM / 8);
  k_c2  <<<KCENT / 4, 256, 0, stream>>>(C, c2);
  k_main<<<(BDIM * NFEAT / FB) * NCB, 512, 0, stream>>>(Xbf, Cbf, c2, cand);
  k_post<<<BDIM * NFEAT / 4, 256, 0, stream>>>(F, A, C, c2, cand, outG, outW);
  k_norm<<<(BDIM * KCENT) / 4, 256, 0, stream>>>(outG);
}

// Round 4
// 216.582 us; speedup vs baseline: 9.2460x; 1.5529x over previous
//
#include <hip/hip_runtime.h>
#include <hip/hip_bf16.h>
#include <math.h>

#define BDIM  4
#define NFEAT 2048
#define DDIM  256
#define KCENT 16384
#define TK    5
#define NCB   4
#define CBSZ  (KCENT / NCB)   // 4096
#define KB    128             // centroids per tile
#define NT    (CBSZ / KB)     // 32
#define FB    128             // features per block
#define RESC  12              // exactly-rescored candidates per feature
#define NROW  (BDIM * KCENT)  // 65536
#define INFF  (__builtin_inff())

typedef __attribute__((ext_vector_type(4))) float  f32x4;
typedef __attribute__((ext_vector_type(8))) short  short8v;

static __device__ __forceinline__ short f2bf(float x) {
  __hip_bfloat16 h = __float2bfloat16(x);
  return __builtin_bit_cast(short, h);
}

static __device__ __forceinline__ float wsum(float v) {
  v += __shfl_xor(v, 1);  v += __shfl_xor(v, 2);  v += __shfl_xor(v, 4);
  v += __shfl_xor(v, 8);  v += __shfl_xor(v, 16); v += __shfl_xor(v, 32);
  return v;
}
static __device__ __forceinline__ unsigned uwsum(unsigned v) {
  v += __shfl_xor(v, 1);  v += __shfl_xor(v, 2);  v += __shfl_xor(v, 4);
  v += __shfl_xor(v, 8);  v += __shfl_xor(v, 16); v += __shfl_xor(v, 32);
  return v;
}

// ---- fp32 -> bf16 bulk convert ---------------------------------------------
__global__ __launch_bounds__(256) void k_cvt(const float* __restrict__ src,
                                             short* __restrict__ dst, int n8) {
  const int i = blockIdx.x * 256 + threadIdx.x;
  if (i >= n8) return;
  const float4* s = (const float4*)src + (size_t)i * 2;
  const float4 a = s[0], b = s[1];
  short8v o;
  o[0] = f2bf(a.x); o[1] = f2bf(a.y); o[2] = f2bf(a.z); o[3] = f2bf(a.w);
  o[4] = f2bf(b.x); o[5] = f2bf(b.y); o[6] = f2bf(b.z); o[7] = f2bf(b.w);
  ((short8v*)dst)[i] = o;
}

// ---- c2[k] = sum(C[k,:]^2) exact fp32 --------------------------------------
__global__ __launch_bounds__(256) void k_c2(const float* __restrict__ C, float* __restrict__ c2) {
  const int w = threadIdx.x >> 6, l = threadIdx.x & 63;
  const int row = blockIdx.x * 4 + w;
  const float4 v = *(const float4*)(C + (size_t)row * DDIM + l * 4);
  const float ss = wsum(v.x*v.x + v.y*v.y + v.z*v.z + v.w*v.w);
  if (l == 0) c2[row] = ss;
}

// ---- bf16 MFMA distance pass, packed-key top-5, per-feature top-8 ----------
__global__ __launch_bounds__(512, 2) void k_main(
    const short* __restrict__ Xbf, const short* __restrict__ Cbf,
    const float* __restrict__ c2g, uint2* __restrict__ cand)
{
  __shared__ short sC[2][KB * DDIM];   // 2 x 64 KB
  __shared__ float sC2a[CBSZ];         // 16 KB: whole split's biased c2

  const int tid = threadIdx.x;
  const int l = tid & 63, w = tid >> 6;
  const int wm = w & 3, wn = w >> 2;
  const int lrow = l & 15, lk = l >> 4;
  const int cb = blockIdx.x & (NCB - 1), fb = blockIdx.x / NCB;
  const int fbase = fb * FB;
  const size_t coffB = (size_t)cb * CBSZ * (DDIM * 2);

  const int poff = (tid & 15) * 512 + (tid >> 6) * 64 + ((tid >> 4) & 3) * 16;

  auto stage = [&](const char* gsrcB, int buf) {
#pragma unroll
    for (int r = 0; r < 8; ++r) {
      __builtin_amdgcn_global_load_lds(
          (const __attribute__((address_space(1))) void*)(gsrcB + r * 8192 + poff),
          (__attribute__((address_space(3))) void*)((char*)&sC[buf][0] + r * 8192 + tid * 16),
          16, 0, 0);
    }
  };

  stage((const char*)Xbf + (size_t)fbase * 512, 1);
  stage((const char*)Cbf + coffB, 0);
  {
    const f32x4* src = (const f32x4*)(c2g + cb * CBSZ);
    const f32x4 bias = {1024.f, 1024.f, 1024.f, 1024.f};
    f32x4* dst = (f32x4*)sC2a;
    dst[tid * 2]     = src[tid * 2]     + bias;
    dst[tid * 2 + 1] = src[tid * 2 + 1] + bias;
  }
  __syncthreads();

  short8v bfr[4][8];
#pragma unroll
  for (int nf = 0; nf < 4; ++nf) {
    const char* bp = (const char*)&sC[1][0] + (wn * 4 + nf) * 8192 + l * 16;
#pragma unroll
    for (int kk = 0; kk < 8; ++kk)
      bfr[nf][kk] = *(const short8v*)(bp + kk * 1024);
  }
  __syncthreads();   // buf1 free for staging

  const char* a0b0 = (const char*)&sC[0][0] + (wm * 2 + 0) * 8192 + l * 16;
  const char* a1b0 = (const char*)&sC[0][0] + (wm * 2 + 1) * 8192 + l * 16;
  const char* a0b1 = (const char*)&sC[1][0] + (wm * 2 + 0) * 8192 + l * 16;
  const char* a1b1 = (const char*)&sC[1][0] + (wm * 2 + 1) * 8192 + l * 16;

  unsigned kv[4][5];
#pragma unroll
  for (int nf = 0; nf < 4; ++nf)
#pragma unroll
    for (int j = 0; j < 5; ++j) kv[nf][j] = 0xFFFFFFFFu;

  for (int t = 0; t < NT; ++t) {
    const int buf = t & 1;
    if (t + 1 < NT) stage((const char*)Cbf + coffB + (size_t)(t + 1) * (KB * 512), buf ^ 1);

    f32x4 acc[2][4];
    const f32x4 z = {0.f, 0.f, 0.f, 0.f};
#pragma unroll
    for (int mf = 0; mf < 2; ++mf)
#pragma unroll
      for (int nf = 0; nf < 4; ++nf) acc[mf][nf] = z;

    const char* ap0 = buf ? a0b1 : a0b0;
    const char* ap1 = buf ? a1b1 : a1b0;
#pragma unroll
    for (int kk = 0; kk < 8; ++kk) {
      const short8v a0 = *(const short8v*)(ap0 + kk * 1024);
      const short8v a1 = *(const short8v*)(ap1 + kk * 1024);
#pragma unroll
      for (int nf = 0; nf < 4; ++nf) {
        acc[0][nf] = __builtin_amdgcn_mfma_f32_16x16x32_bf16(a0, bfr[nf][kk], acc[0][nf], 0, 0, 0);
        acc[1][nf] = __builtin_amdgcn_mfma_f32_16x16x32_bf16(a1, bfr[nf][kk], acc[1][nf], 0, 0, 0);
      }
    }

    const f32x4 cb0 = *(const f32x4*)&sC2a[t * KB + wm * 32 + lk * 4];
    const f32x4 cb1 = *(const f32x4*)&sC2a[t * KB + wm * 32 + 16 + lk * 4];
#pragma unroll
    for (int mf = 0; mf < 2; ++mf)
#pragma unroll
      for (int r = 0; r < 4; ++r) {
        const float c2v = mf ? cb1[r] : cb0[r];
        const unsigned q = (unsigned)(t * 8 + mf * 4 + r);
#pragma unroll
        for (int nf = 0; nf < 4; ++nf) {
          const float sqb = fmaf(-2.0f, acc[mf][nf][r], c2v);
          unsigned x = (__float_as_uint(sqb) & 0xFFFFFF00u) | q;
#define INS(S) { const unsigned lo = kv[nf][S] < x ? kv[nf][S] : x; \
                 x = kv[nf][S] < x ? x : kv[nf][S]; kv[nf][S] = lo; }
          INS(0) INS(1) INS(2) INS(3)
          kv[nf][4] = kv[nf][4] < x ? kv[nf][4] : x;
#undef INS
        }
      }
    __syncthreads();
  }

  unsigned* mb = (unsigned*)&sC[0][0];
#pragma unroll
  for (int nf = 0; nf < 4; ++nf) {
    const int fl = wn * 64 + nf * 16 + lrow;
    const int s = wm * 4 + lk;
#pragma unroll
    for (int j = 0; j < 5; ++j) mb[fl * 81 + s * 5 + j] = kv[nf][j];
  }
  __syncthreads();

  if (tid < FB) {
    unsigned bv[8], bi[8];
#pragma unroll
    for (int j = 0; j < 8; ++j) { bv[j] = 0xFFFFFFFFu; bi[j] = 0; }
    const unsigned* row = mb + tid * 81;
    for (int s = 0; s < 16; ++s) {
      const unsigned aux = (unsigned)(cb * CBSZ + (s >> 2) * 32 + (s & 3) * 4);
#pragma unroll
      for (int j = 0; j < 5; ++j) {
        const unsigned v = row[s * 5 + j];
        const unsigned q = v & 255u;
        const unsigned ci = aux + (q >> 3) * 128 + ((q >> 2) & 1u) * 16 + (q & 3u);
        const bool s0 = v < bv[0], s1 = v < bv[1], s2 = v < bv[2], s3 = v < bv[3],
                   s4 = v < bv[4], s5 = v < bv[5], s6 = v < bv[6], s7 = v < bv[7];
        bv[7] = s6 ? bv[6] : (s7 ? v : bv[7]);  bi[7] = s6 ? bi[6] : (s7 ? ci : bi[7]);
        bv[6] = s5 ? bv[5] : (s6 ? v : bv[6]);  bi[6] = s5 ? bi[5] : (s6 ? ci : bi[6]);
        bv[5] = s4 ? bv[4] : (s5 ? v : bv[5]);  bi[5] = s4 ? bi[4] : (s5 ? ci : bi[5]);
        bv[4] = s3 ? bv[3] : (s4 ? v : bv[4]);  bi[4] = s3 ? bi[3] : (s4 ? ci : bi[4]);
        bv[3] = s2 ? bv[2] : (s3 ? v : bv[3]);  bi[3] = s2 ? bi[2] : (s3 ? ci : bi[3]);
        bv[2] = s1 ? bv[1] : (s2 ? v : bv[2]);  bi[2] = s1 ? bi[1] : (s2 ? ci : bi[2]);
        bv[1] = s0 ? bv[0] : (s1 ? v : bv[1]);  bi[1] = s0 ? bi[0] : (s1 ? ci : bi[1]);
        bv[0] = s0 ? v : bv[0];                 bi[0] = s0 ? ci : bi[0];
      }
    }
    uint2* cp = cand + ((size_t)(fbase + tid) * NCB + cb) * 8;
#pragma unroll
    for (int j = 0; j < 8; ++j) cp[j] = make_uint2(bv[j], bi[j]);
  }
}

// ---- select: bitonic top-12, exact rescore, top-5, softmax -> sel + counts -
__global__ __launch_bounds__(256) void k_select(
    const float* __restrict__ F, const float* __restrict__ A,
    const float* __restrict__ C, const float* __restrict__ c2g,
    const uint2* __restrict__ cand, uint4* __restrict__ sel,
    unsigned* __restrict__ cnt)
{
  const int l = threadIdx.x & 63, w = threadIdx.x >> 6;
  const int f = blockIdx.x * 4 + w;
  const int b = f >> 11;

  const float4 xv = *(const float4*)(F + (size_t)f * DDIM + l * 4);
  const float x2 = wsum(xv.x*xv.x + xv.y*xv.y + xv.z*xv.z + xv.w*xv.w);

  unsigned key = 0xFFFFFFFFu, ci = 0u;
  if (l < 32) { const uint2 e = cand[(size_t)f * 32 + l]; key = e.x; ci = e.y; }

  // bitonic sort of 32 keys in lanes 0..31 (lanes 32+ sort garbage separately)
#pragma unroll
  for (int k = 2; k <= 32; k <<= 1) {
#pragma unroll
    for (int j = k >> 1; j >= 1; j >>= 1) {
      const unsigned pk = __shfl_xor(key, j);
      const unsigned pc = __shfl_xor(ci, j);
      const bool keepMin = (((l & j) == 0) == ((l & k) == 0));
      const bool take = keepMin ? (pk < key) : (pk > key);
      if (take) { key = pk; ci = pc; }
    }
  }

  int sidx[RESC];
#pragma unroll
  for (int j = 0; j < RESC; ++j) sidx[j] = __shfl((int)ci, j);
  float4 cv[RESC];
#pragma unroll
  for (int j = 0; j < RESC; ++j)
    cv[j] = *(const float4*)(C + (size_t)sidx[j] * DDIM + l * 4);
  float sq[RESC];
#pragma unroll
  for (int j = 0; j < RESC; ++j) {
    const float d = wsum(xv.x*cv[j].x + xv.y*cv[j].y + xv.z*cv[j].z + xv.w*cv[j].w);
    sq[j] = fmaxf(fmaf(-2.0f, d, x2 + c2g[sidx[j]]), 0.0f);
  }

  // top-5 of 12 (uniform across lanes, register-only)
  unsigned sk[RESC];
#pragma unroll
  for (int j = 0; j < RESC; ++j) sk[j] = (__float_as_uint(sq[j]) & ~15u) | (unsigned)j;
  float ssq[TK]; int jm5[TK];
#pragma unroll
  for (int s = 0; s < TK; ++s) {
    unsigned m = 0xFFFFFFFFu;
#pragma unroll
    for (int j = 0; j < RESC; ++j) m = sk[j] < m ? sk[j] : m;
#pragma unroll
    for (int j = 0; j < RESC; ++j) sk[j] = (sk[j] == m) ? 0xFFFFFFFFu : sk[j];
    ssq[s] = __uint_as_float(m & ~15u);
    jm5[s] = (int)(m & 15u);
  }
  int k5[TK];
#pragma unroll
  for (int s = 0; s < TK; ++s) k5[s] = __shfl((int)ci, jm5[s]);

  const float d0 = sqrtf(ssq[0]);
  float p5[TK]; float sum = 0.f;
#pragma unroll
  for (int s = 0; s < TK; ++s) { p5[s] = expf(d0 - sqrtf(ssq[s])); sum += p5[s]; }
  const float inv = 1.0f / sum;
  const float att = A[f];

  float p = p5[0]; int ks = k5[0];
  p = (l == 1) ? p5[1] : p;  ks = (l == 1) ? k5[1] : ks;
  p = (l == 2) ? p5[2] : p;  ks = (l == 2) ? k5[2] : ks;
  p = (l == 3) ? p5[3] : p;  ks = (l == 3) ? k5[3] : ks;
  p = (l == 4) ? p5[4] : p;  ks = (l == 4) ? k5[4] : ks;
  p *= inv;
  if (l < TK) {
    sel[(size_t)f * TK + l] = make_uint4((unsigned)ks, __float_as_uint(p),
                                         __float_as_uint(att * p), 0u);
    atomicAdd(&cnt[b * KCENT + ks], 1u);
  }
}

// ---- prefix scan over cnt[65536]: 3 small kernels --------------------------
__global__ __launch_bounds__(256) void k_scan1(const unsigned* __restrict__ cnt,
                                               unsigned* __restrict__ bsum) {
  __shared__ unsigned ws4[4];
  const int t = threadIdx.x, lane = t & 63, w = t >> 6;
  const uint4 c = *(const uint4*)&cnt[(blockIdx.x * 256 + t) * 4];
  unsigned v = uwsum(c.x + c.y + c.z + c.w);
  if (lane == 0) ws4[w] = v;
  __syncthreads();
  if (t == 0) bsum[blockIdx.x] = ws4[0] + ws4[1] + ws4[2] + ws4[3];
}

__global__ __launch_bounds__(64) void k_scan2(const unsigned* __restrict__ bsum,
                                              unsigned* __restrict__ boff) {
  const int l = threadIdx.x;
  unsigned v = bsum[l];
  const unsigned own = v;
#pragma unroll
  for (int d = 1; d < 64; d <<= 1) {
    const unsigned n = __shfl_up(v, d);
    if (l >= d) v += n;
  }
  boff[l] = v - own;
}

__global__ __launch_bounds__(256) void k_scan3(const unsigned* __restrict__ cnt,
                                               const unsigned* __restrict__ boff,
                                               unsigned* __restrict__ off) {
  __shared__ unsigned wt[4];
  const int t = threadIdx.x, lane = t & 63, w = t >> 6;
  const int i0 = (blockIdx.x * 256 + t) * 4;
  const uint4 c = *(const uint4*)&cnt[i0];
  const unsigned ts = c.x + c.y + c.z + c.w;
  unsigned v = ts;
#pragma unroll
  for (int d = 1; d < 64; d <<= 1) {
    const unsigned n = __shfl_up(v, d);
    if (lane >= d) v += n;
  }
  if (lane == 63) wt[w] = v;
  __syncthreads();
  unsigned wb = boff[blockIdx.x];
  if (w > 0) wb += wt[0];
  if (w > 1) wb += wt[1];
  if (w > 2) wb += wt[2];
  const unsigned ex = wb + v - ts;
  uint4 o;
  o.x = ex; o.y = ex + c.x; o.z = o.y + c.y; o.w = o.z + c.z;
  *(uint4*)&off[i0] = o;
}

// ---- fill CSR entries ------------------------------------------------------
__global__ __launch_bounds__(256) void k_fill(const uint4* __restrict__ sel,
                                              unsigned* __restrict__ off,
                                              uint4* __restrict__ ent) {
  const int f = blockIdx.x * 256 + threadIdx.x;
  const int b = f >> 11;
#pragma unroll
  for (int s = 0; s < TK; ++s) {
    const uint4 e = sel[(size_t)f * TK + s];
    const unsigned pos = atomicAdd(&off[b * KCENT + (int)e.x], 1u);
    ent[pos] = make_uint4((unsigned)f, e.y, e.z, 0u);
  }
}

// ---- per-row gather + normalize + weight (atomic-free, single write) -------
__global__ __launch_bounds__(256) void k_out(
    const float* __restrict__ F, const float* __restrict__ C,
    const unsigned* __restrict__ cnt, const unsigned* __restrict__ offend,
    const uint4* __restrict__ ent, float* __restrict__ outG, float* __restrict__ outW)
{
  const int l = threadIdx.x & 63, w = threadIdx.x >> 6;
  const int row = blockIdx.x * 4 + w;
  const int k = row & (KCENT - 1);
  const unsigned c = cnt[row];
  const unsigned s0 = offend[row] - c;   // off was mutated to end by k_fill

  float4 acc = {0.f, 0.f, 0.f, 0.f};
  float csum = 0.f, pmax = 0.f;
  for (unsigned j = 0; j < c; ++j) {
    const uint4 E = ent[s0 + j];
    const float coef = __uint_as_float(E.z);
    const float pp = __uint_as_float(E.y);
    const float4 xr = *(const float4*)(F + (size_t)E.x * DDIM + l * 4);
    acc.x = fmaf(coef, xr.x, acc.x);
    acc.y = fmaf(coef, xr.y, acc.y);
    acc.z = fmaf(coef, xr.z, acc.z);
    acc.w = fmaf(coef, xr.w, acc.w);
    csum += coef; pmax = fmaxf(pmax, pp);
  }
  float4 o = {0.f, 0.f, 0.f, 0.f};
  if (c > 0) {
    const float4 cv = *(const float4*)(C + (size_t)k * DDIM + l * 4);
    o.x = fmaf(-csum, cv.x, acc.x);
    o.y = fmaf(-csum, cv.y, acc.y);
    o.z = fmaf(-csum, cv.z, acc.z);
    o.w = fmaf(-csum, cv.w, acc.w);
    const float ss = wsum(o.x*o.x + o.y*o.y + o.z*o.z + o.w*o.w);
    const float sc = 1.0f / (sqrtf(ss) + 1e-6f);
    o.x *= sc; o.y *= sc; o.z *= sc; o.w *= sc;
  }
  *(float4*)(outG + (size_t)row * DDIM + l * 4) = o;
  if (l == 0) outW[row] = pmax;
}

extern "C" void kernel_launch(void* const* d_in, const int* in_sizes, int n_in,
                              void* d_out, int out_size, void* d_ws, size_t ws_size,
                              hipStream_t stream) {
  const float* F = (const float*)d_in[0];
  const float* A = (const float*)d_in[1];
  const float* C = (const float*)d_in[2];
  float* outG = (float*)d_out;
  float* outW = outG + (size_t)BDIM * KCENT * DDIM;

  char* ws = (char*)d_ws;
  short*    Xbf  = (short*)ws;                       // [0,4M)   dead after k_main
  short*    Cbf  = (short*)(ws + (4u << 20));        // [4M,12M)
  float*    c2   = (float*)(ws + (12u << 20));       // 64 KB
  uint2*    cand = (uint2*)(ws + (13u << 20));       // 2 MB
  // overlay region [0,4M) reused after k_main:
  uint4*    sel  = (uint4*)ws;                       // 640 KB
  unsigned* cnt  = (unsigned*)(ws + (1u << 20));     // 256 KB
  unsigned* off  = (unsigned*)(ws + (1536u << 10));  // 256 KB
  unsigned* bsum = (unsigned*)(ws + (1792u << 10));  // 256 B
  unsigned* boff = (unsigned*)(ws + (1796u << 10));  // 256 B
  uint4*    ent  = (uint4*)(ws + (2u << 20));        // 640 KB

  k_cvt   <<<BDIM * NFEAT * DDIM / 8 / 256, 256, 0, stream>>>(F, Xbf, BDIM * NFEAT * DDIM / 8);
  k_cvt   <<<KCENT * DDIM / 8 / 256, 256, 0, stream>>>(C, Cbf, KCENT * DDIM / 8);
  k_c2    <<<KCENT / 4, 256, 0, stream>>>(C, c2);
  k_main  <<<(BDIM * NFEAT / FB) * NCB, 512, 0, stream>>>(Xbf, Cbf, c2, cand);
  hipMemsetAsync(cnt, 0, NROW * sizeof(unsigned), stream);
  k_select<<<BDIM * NFEAT / 4, 256, 0, stream>>>(F, A, C, c2, cand, sel, cnt);
  k_scan1 <<<NROW / 1024, 256, 0, stream>>>(cnt, bsum);
  k_scan2 <<<1, 64, 0, stream>>>(bsum, boff);
  k_scan3 <<<NROW / 1024, 256, 0, stream>>>(cnt, boff, off);
  k_fill  <<<BDIM * NFEAT / 256, 256, 0, stream>>>(sel, off, ent);
  k_out   <<<NROW / 4, 256, 0, stream>>>(F, C, cnt, off, ent, outG, outW);
}